// Round 7
// baseline (524.530 us; speedup 1.0000x reference)
//
#include <hip/hip_runtime.h>
#include <math.h>

// AttentionPool: scores = einsum("btd,d->bt"), masked softmax over T,
// pooled = einsum("bt,btd->bd").  B=16, T=4096, D=1024, f32.
//
// Fused single-pass online-softmax pooling: read hidden_states exactly once.
// grid = B*blocksPerB blocks (256 thr = 4 waves). Each wave owns
// tokensPerWave contiguous tokens; lanes split D (4 x float4, coalesced).
// Wave butterfly-reduce the dot, deferred-rescale online softmax update.
// Cross-wave merge in LDS -> partial (m, l, acc[1024]) per block into d_ws.
// Last-finishing block per b (device-scope atomic counter) combines all
// partials of its b and writes the final normalized row.

typedef float f32x4 __attribute__((ext_vector_type(4)));

__global__ __launch_bounds__(256) void ap_fused(
    const float* __restrict__ hs, const int* __restrict__ mask,
    const float* __restrict__ ctx,
    float* __restrict__ accs, float* __restrict__ ms, float* __restrict__ ls,
    int* __restrict__ counters, float* __restrict__ out,
    int T, int blocksPerB, int tokensPerWave)
{
    const int D = 1024;            // layout assumption: D == 1024 (4*64*4)
    int bi    = blockIdx.x;
    int b     = bi / blocksPerB;
    int chunk = bi - b * blocksPerB;
    int wave  = threadIdx.x >> 6;
    int lane  = threadIdx.x & 63;
    int tid   = threadIdx.x;

    int t0 = chunk * (tokensPerWave * 4) + wave * tokensPerWave;

    // context vector fragment: f32x4 index = j*64 + lane
    const f32x4* ctx4 = (const f32x4*)ctx;
    f32x4 c0 = ctx4[0 * 64 + lane];
    f32x4 c1 = ctx4[1 * 64 + lane];
    f32x4 c2 = ctx4[2 * 64 + lane];
    f32x4 c3 = ctx4[3 * 64 + lane];

    f32x4 a0 = {0.f,0.f,0.f,0.f}, a1 = {0.f,0.f,0.f,0.f};
    f32x4 a2 = {0.f,0.f,0.f,0.f}, a3 = {0.f,0.f,0.f,0.f};
    float m = -INFINITY, l = 0.0f;

    const f32x4* hp = (const f32x4*)hs + ((size_t)b * T + t0) * (D / 4);
    const int*   mp = mask + (size_t)b * T + t0;

    for (int i = 0; i < tokensPerWave; ++i) {
        const f32x4* row = hp + (size_t)i * (D / 4);
        f32x4 h0 = __builtin_nontemporal_load(&row[0 * 64 + lane]);
        f32x4 h1 = __builtin_nontemporal_load(&row[1 * 64 + lane]);
        f32x4 h2 = __builtin_nontemporal_load(&row[2 * 64 + lane]);
        f32x4 h3 = __builtin_nontemporal_load(&row[3 * 64 + lane]);

        float p = 0.0f;
        p = fmaf(h0.x, c0.x, p); p = fmaf(h0.y, c0.y, p);
        p = fmaf(h0.z, c0.z, p); p = fmaf(h0.w, c0.w, p);
        p = fmaf(h1.x, c1.x, p); p = fmaf(h1.y, c1.y, p);
        p = fmaf(h1.z, c1.z, p); p = fmaf(h1.w, c1.w, p);
        p = fmaf(h2.x, c2.x, p); p = fmaf(h2.y, c2.y, p);
        p = fmaf(h2.z, c2.z, p); p = fmaf(h2.w, c2.w, p);
        p = fmaf(h3.x, c3.x, p); p = fmaf(h3.y, c3.y, p);
        p = fmaf(h3.z, c3.z, p); p = fmaf(h3.w, c3.w, p);

        // full-wave butterfly reduce (64 lanes) — all lanes end with the sum
        #pragma unroll
        for (int off = 32; off > 0; off >>= 1) p += __shfl_xor(p, off);

        if (mp[i] != 0) {           // wave-uniform branch
            if (p > m) {            // deferred rescale: rare (O(log T) per chunk)
                float c = __expf(m - p);   // m = -inf first time -> c = 0
                l *= c;
                a0 *= c; a1 *= c; a2 *= c; a3 *= c;
                m = p;
            }
            float w = __expf(p - m);
            l += w;
            a0.x = fmaf(w, h0.x, a0.x); a0.y = fmaf(w, h0.y, a0.y);
            a0.z = fmaf(w, h0.z, a0.z); a0.w = fmaf(w, h0.w, a0.w);
            a1.x = fmaf(w, h1.x, a1.x); a1.y = fmaf(w, h1.y, a1.y);
            a1.z = fmaf(w, h1.z, a1.z); a1.w = fmaf(w, h1.w, a1.w);
            a2.x = fmaf(w, h2.x, a2.x); a2.y = fmaf(w, h2.y, a2.y);
            a2.z = fmaf(w, h2.z, a2.z); a2.w = fmaf(w, h2.w, a2.w);
            a3.x = fmaf(w, h3.x, a3.x); a3.y = fmaf(w, h3.y, a3.y);
            a3.z = fmaf(w, h3.z, a3.z); a3.w = fmaf(w, h3.w, a3.w);
        }
    }

    // ---- cross-wave merge in LDS ----
    __shared__ float s_m[4];
    __shared__ float s_lf[4];
    __shared__ f32x4 s_acc[4][256];   // 16 KB
    __shared__ int   s_last;

    if (lane == 0) s_m[wave] = m;
    __syncthreads();
    float M = fmaxf(fmaxf(s_m[0], s_m[1]), fmaxf(s_m[2], s_m[3]));
    float f = (m == -INFINITY) ? 0.0f : __expf(m - M);
    if (lane == 0) s_lf[wave] = l * f;
    s_acc[wave][0 * 64 + lane] = a0 * f;
    s_acc[wave][1 * 64 + lane] = a1 * f;
    s_acc[wave][2 * 64 + lane] = a2 * f;
    s_acc[wave][3 * 64 + lane] = a3 * f;
    __syncthreads();

    f32x4 v0 = s_acc[0][tid], v1 = s_acc[1][tid], v2 = s_acc[2][tid], v3 = s_acc[3][tid];
    f32x4 r = (v0 + v1) + (v2 + v3);

    f32x4* accs4 = (f32x4*)(accs + (size_t)bi * D);
    accs4[tid] = r;
    if (tid == 0) {
        ms[bi] = M;
        ls[bi] = (s_lf[0] + s_lf[1]) + (s_lf[2] + s_lf[3]);
    }

    // ---- last-block-per-b combine (device-scope) ----
    __threadfence();               // release: partials visible device-wide
    __syncthreads();
    if (tid == 0) {
        int old = atomicAdd(&counters[b], 1);   // device-scope by default
        s_last = (old == blocksPerB - 1) ? 1 : 0;
    }
    __syncthreads();
    if (!s_last) return;
    __threadfence();               // acquire: see all other blocks' partials

    const float* mB = ms + (size_t)b * blocksPerB;
    const float* lB = ls + (size_t)b * blocksPerB;

    float M2 = -INFINITY;
    for (int c = 0; c < blocksPerB; ++c) M2 = fmaxf(M2, mB[c]);
    float L2 = 0.0f;
    for (int c = 0; c < blocksPerB; ++c) {
        float mc = mB[c];
        float fc = (mc == -INFINITY) ? 0.0f : __expf(mc - M2);
        L2 += lB[c] * fc;
    }

    f32x4 racc = {0.f,0.f,0.f,0.f};
    const f32x4* allAccs4 = (const f32x4*)accs;
    for (int c = 0; c < blocksPerB; ++c) {
        float mc = mB[c];
        float fc = (mc == -INFINITY) ? 0.0f : __expf(mc - M2);
        f32x4 v = allAccs4[((size_t)b * blocksPerB + c) * 256 + tid];
        racc.x = fmaf(v.x, fc, racc.x); racc.y = fmaf(v.y, fc, racc.y);
        racc.z = fmaf(v.z, fc, racc.z); racc.w = fmaf(v.w, fc, racc.w);
    }
    float inv = 1.0f / L2;
    ((f32x4*)out)[(size_t)b * 256 + tid] = racc * inv;
}

extern "C" void kernel_launch(void* const* d_in, const int* in_sizes, int n_in,
                              void* d_out, int out_size, void* d_ws, size_t ws_size,
                              hipStream_t stream)
{
    const float* hs   = (const float*)d_in[0];
    const int*   mask = (const int*)d_in[1];
    const float* ctx  = (const float*)d_in[2];

    const int D = 1024;
    int B = out_size / D;          // 16
    int T = in_sizes[1] / B;       // 4096

    // chunking: 64 chunks/b -> 1024 blocks (4/CU); shrink if ws too small
    int blocksPerB = 64;
    while (blocksPerB > 1 &&
           ((T % (4 * blocksPerB)) != 0 ||
            256 + (size_t)B * blocksPerB * (size_t)(D + 2) * sizeof(float) > ws_size))
        blocksPerB >>= 1;
    int tokensPerWave = T / (4 * blocksPerB);
    int numP = B * blocksPerB;

    // ws layout: [counters: B ints, padded to 256 B][accs][ms][ls]
    int*   counters = (int*)d_ws;
    float* accs     = (float*)((char*)d_ws + 256);
    float* ms       = accs + (size_t)numP * D;
    float* ls       = ms + numP;

    (void)hipMemsetAsync(counters, 0, 256, stream);   // ws is re-poisoned 0xAA each call
    ap_fused<<<numP, 256, 0, stream>>>(hs, mask, ctx, accs, ms, ls,
                                       counters, (float*)d_out,
                                       T, blocksPerB, tokensPerWave);
}